// Round 9
// baseline (233.371 us; speedup 1.0000x reference)
//
#include <hip/hip_runtime.h>
#include <hip/hip_bf16.h>

#define DD 1024
#define BM 128
#define BN 128
#define BK 64
#define NKT (DD / BK)   // 16 K-tiles
#define TAU 32.0f
#define PTH 0.1f
#define BIGF 3.0e38f

typedef __attribute__((ext_vector_type(8))) short bf16x8;
typedef __attribute__((ext_vector_type(4))) float f32x4;

__device__ __forceinline__ unsigned short f2bf(float f) {
  unsigned u = __float_as_uint(f);
  u = (u + 0x7FFFu + ((u >> 16) & 1u)) >> 16;
  return (unsigned short)u;
}

// sorted-ascending top-5-smallest insert via med3: 5 independent VALU ops
__device__ __forceinline__ void insert5(float (&t)[5], float v) {
  float t0 = t[0], t1 = t[1], t2 = t[2], t3 = t[3], t4 = t[4];
  t[0] = fminf(t0, v);
  t[1] = __builtin_amdgcn_fmed3f(v, t0, t1);
  t[2] = __builtin_amdgcn_fmed3f(v, t1, t2);
  t[3] = __builtin_amdgcn_fmed3f(v, t2, t3);
  t[4] = __builtin_amdgcn_fmed3f(v, t3, t4);
}

__device__ __forceinline__ void gload16(const unsigned short* g, unsigned short* l) {
  __builtin_amdgcn_global_load_lds(
      (const __attribute__((address_space(1))) void*)g,
      (__attribute__((address_space(3))) void*)l, 16, 0, 0);
}

// one wave per row: squared norm (f32) + bf16 cast of X
__global__ void prep_kernel(const float* __restrict__ x, unsigned short* __restrict__ xbf,
                            float* __restrict__ sq) {
  const int row  = blockIdx.x * 4 + (threadIdx.x >> 6);
  const int lane = threadIdx.x & 63;
  const float4* xr = reinterpret_cast<const float4*>(x) + (size_t)row * (DD / 4);
  float s = 0.f;
  #pragma unroll
  for (int i = 0; i < 4; ++i) {
    float4 v = xr[lane + 64 * i];
    s += v.x * v.x + v.y * v.y + v.z * v.z + v.w * v.w;
    ushort4 b;
    b.x = f2bf(v.x); b.y = f2bf(v.y); b.z = f2bf(v.z); b.w = f2bf(v.w);
    *reinterpret_cast<ushort4*>(xbf + (size_t)row * DD + (size_t)(lane + 64 * i) * 4) = b;
  }
  #pragma unroll
  for (int off = 32; off > 0; off >>= 1) s += __shfl_xor(s, off, 64);
  if (lane == 0) sq[row] = s;
}

// Symmetric flash top-k over upper-triangle 128x128 block-pairs (I,J), 8x8
// super-tiles + XCD swizzle. K-loop: A double-buffered in LDS (swizzled
// gload_lds); B direct global->VGPR double-set prefetched 1 tile ahead;
// one raw s_barrier + one counted vmcnt(8) per iter — loads span barriers.
__global__ __launch_bounds__(256, 3)
void gemm_topk_kernel(const unsigned short* __restrict__ xbf, const float* __restrict__ sq,
                      float* __restrict__ partial, int N) {
  __shared__ union ShMem {
    unsigned short A[2][BM * BK];  // 2 x 16 KB A double buffer
    float mrg[64 * 161];           // row-merge: row*161 + contrib*5 + j  (41.2 KB)
    float mrgc[128 * 41];          // col-merge: col*41 + contrib*5 + j   (21 KB)
  } sh;
  static_assert(sizeof(ShMem) <= 65536, "LDS over 64KB");

  const int tid  = threadIdx.x;
  const int lane = tid & 63;
  const int wid  = tid >> 6;
  const int wr   = wid >> 1;   // 0..1 -> 64-row half
  const int wc   = wid & 1;    // 0..1 -> 64-col half
  const int l15  = lane & 15;
  const int l4   = lane >> 4;  // 0..3

  const int NBv = N / BM;      // 64 block-rows
  const int NSB = NBv / 8;     // 8 super-rows

  // bijective chunked XCD swizzle (gridDim.x divisible by 8)
  const int chunk = gridDim.x >> 3;
  const int swz = (blockIdx.x & 7) * chunk + (blockIdx.x >> 3);
  const int sp  = swz >> 6;    // super-pair (triangle over NSB)
  const int sub = swz & 63;

  int SI = 0;
  #define TSTART(i) ((i) * NSB - ((i) * ((i) - 1)) / 2)
  while (SI + 1 < NSB && TSTART(SI + 1) <= sp) ++SI;
  const int SJ = SI + (sp - TSTART(SI));
  #undef TSTART
  const int si = sub >> 3, sj = sub & 7;
  if (SI == SJ && si > sj) return;  // lower-triangle sub-pair of diagonal super-pair
  const int I = SI * 8 + si, J = SJ * 8 + sj;

  const int row0 = I * BM;
  const int cb   = J * BM;
  const bool diag = (I == J);

  // A staging source (pre-swizzled): inst j covers LDS slots j*64+lane
  const int lr = lane >> 3;
  const int lc = (lane & 7) ^ lr;
  const size_t offl = (size_t)lr * DD + lc * 8;
  const int jbase = wid * 4;
  const unsigned short* srcA = xbf + (size_t)row0 * DD + offl;
  // B direct-load base: row = cb + wc*64 + ni*16 + l15, elem chunk l4*8 (+ks*32)
  const unsigned short* srcB = xbf + (size_t)(cb + wc * 64 + l15) * DD + l4 * 8;

  // A fragment read swizzle
  const int xs0 = ((l4) ^ (l15 & 7)) * 8;
  const int xs1 = ((4 + l4) ^ (l15 & 7)) * 8;

  f32x4 acc[4][4];
  #pragma unroll
  for (int mi = 0; mi < 4; ++mi)
    #pragma unroll
    for (int ni = 0; ni < 4; ++ni) {
      f32x4 z; z[0] = 0.f; z[1] = 0.f; z[2] = 0.f; z[3] = 0.f;
      acc[mi][ni] = z;
    }

  bf16x8 bs0[8], bs1[8];  // B fragment double set (static indices only)

#define LOADB(set, t) { const size_t kk = (size_t)(t) * BK;                       \
    _Pragma("unroll") for (int ni = 0; ni < 4; ++ni) {                            \
      const unsigned short* bp = srcB + (size_t)ni * 16 * DD + kk;                \
      set[ni * 2]     = *reinterpret_cast<const bf16x8*>(bp);                     \
      set[ni * 2 + 1] = *reinterpret_cast<const bf16x8*>(bp + 32); } }

#define STAGEA(t, buf) { const size_t kk = (size_t)(t) * BK;                      \
    _Pragma("unroll") for (int jj = 0; jj < 4; ++jj) {                            \
      const int j = jbase + jj;                                                   \
      gload16(srcA + (size_t)j * 8 * DD + kk, (buf) + j * 512); } }

#define COMPUTE(buf, bset) {                                                      \
    _Pragma("unroll") for (int ks = 0; ks < 2; ++ks) {                            \
      const int xs = ks ? xs1 : xs0;                                              \
      bf16x8 af[4];                                                               \
      _Pragma("unroll") for (int mi = 0; mi < 4; ++mi)                            \
        af[mi] = *reinterpret_cast<const bf16x8*>((buf) + (wr * 64 + mi * 16 + l15) * BK + xs); \
      _Pragma("unroll") for (int mi = 0; mi < 4; ++mi)                            \
        _Pragma("unroll") for (int ni = 0; ni < 4; ++ni)                          \
          acc[mi][ni] = __builtin_amdgcn_mfma_f32_16x16x32_bf16(af[mi], bset[ni * 2 + ks], acc[mi][ni], 0, 0, 0); } }

  // prologue: B(0) then A(0) -> buf0  (order matters for vmcnt counting)
  LOADB(bs0, 0);
  STAGEA(0, sh.A[0]);

  for (int tp = 0; tp < NKT / 2; ++tp) {
    const int t0 = tp * 2;
    // even iter t0: compute buf0/bs0; prefetch B(t0+1)->bs1, A(t0+1)->buf1
    LOADB(bs1, t0 + 1);
    // own B(t0)+A(t0) drained BEFORE barrier -> visible to all after it; B(t0+1) stays in flight
    asm volatile("s_waitcnt vmcnt(8)" ::: "memory");
    __builtin_amdgcn_s_barrier();
    COMPUTE(sh.A[0], bs0);
    STAGEA(t0 + 1, sh.A[1]);   // writes buf1 while others still read buf0: disjoint
    // odd iter t0+1: compute buf1/bs1; prefetch into bs0/buf0
    if (tp + 1 < NKT / 2) {
      LOADB(bs0, t0 + 2);
      asm volatile("s_waitcnt vmcnt(8)" ::: "memory");
      __builtin_amdgcn_s_barrier();
      COMPUTE(sh.A[1], bs1);
      STAGEA(t0 + 2, sh.A[0]);
    } else {
      asm volatile("s_waitcnt vmcnt(0)" ::: "memory");
      __builtin_amdgcn_s_barrier();
      COMPUTE(sh.A[1], bs1);
    }
  }

  // d^2 = sq_r + sq_c - 2*dot; fold row-side (t5r) and, off-diag, col-side (t5c)
  float t5r[16][5], t5c[4][5];
  #pragma unroll
  for (int i = 0; i < 16; ++i)
    #pragma unroll
    for (int j = 0; j < 5; ++j) t5r[i][j] = BIGF;
  #pragma unroll
  for (int i = 0; i < 4; ++i)
    #pragma unroll
    for (int j = 0; j < 5; ++j) t5c[i][j] = BIGF;

  float sqr_[16];
  #pragma unroll
  for (int mi = 0; mi < 4; ++mi)
    #pragma unroll
    for (int r = 0; r < 4; ++r)
      sqr_[mi * 4 + r] = sq[row0 + wr * 64 + mi * 16 + l4 * 4 + r];

  #pragma unroll
  for (int ni = 0; ni < 4; ++ni) {
    const int gc = cb + wc * 64 + ni * 16 + l15;
    const float sqc = sq[gc];
    #pragma unroll
    for (int mi = 0; mi < 4; ++mi) {
      #pragma unroll
      for (int r = 0; r < 4; ++r) {
        float v = fmaf(-2.0f, acc[mi][ni][r], sqr_[mi * 4 + r] + sqc);
        if (diag) {
          const int gr = row0 + wr * 64 + mi * 16 + l4 * 4 + r;
          v = (gc == gr) ? BIGF : v;  // exclude self
        }
        insert5(t5r[mi * 4 + r], v);
        if (!diag) insert5(t5c[ni], v);
      }
    }
  }

  // row-side merge in two passes (64 rows each; 32 contributors per row) -> slot J
  #pragma unroll
  for (int pass = 0; pass < 2; ++pass) {
    __syncthreads();
    if (wr == pass) {
      #pragma unroll
      for (int mi = 0; mi < 4; ++mi)
        #pragma unroll
        for (int r = 0; r < 4; ++r)
          #pragma unroll
          for (int j = 0; j < 5; ++j)
            sh.mrg[(mi * 16 + l4 * 4 + r) * 161 + (wc * 16 + l15) * 5 + j] = t5r[mi * 4 + r][j];
    }
    __syncthreads();
    if (tid < 64) {
      float m[5] = {BIGF, BIGF, BIGF, BIGF, BIGF};
      for (int s2 = 0; s2 < 32; ++s2)
        #pragma unroll
        for (int j = 0; j < 5; ++j)
          insert5(m, sh.mrg[tid * 161 + s2 * 5 + j]);
      float* p = partial + ((size_t)(row0 + pass * 64 + tid) * NBv + J) * 5;
      #pragma unroll
      for (int j = 0; j < 5; ++j) p[j] = m[j];
    }
  }

  // col-side merge (128 cols; 8 contributors per col) -> rows of block J, slot I
  if (!diag) {
    __syncthreads();
    #pragma unroll
    for (int ni = 0; ni < 4; ++ni)
      #pragma unroll
      for (int j = 0; j < 5; ++j)
        sh.mrgc[(wc * 64 + ni * 16 + l15) * 41 + (wr * 4 + l4) * 5 + j] = t5c[ni][j];
    __syncthreads();
    if (tid < 128) {
      float m[5] = {BIGF, BIGF, BIGF, BIGF, BIGF};
      #pragma unroll
      for (int s2 = 0; s2 < 8; ++s2)
        #pragma unroll
        for (int j = 0; j < 5; ++j)
          insert5(m, sh.mrgc[tid * 41 + s2 * 5 + j]);
      float* p = partial + ((size_t)(cb + tid) * NBv + I) * 5;
      #pragma unroll
      for (int j = 0; j < 5; ++j) p[j] = m[j];
    }
  }
}

// one wave per row: parallel load of 64 slot-top5s + butterfly shuffle merge
__global__ void weight_kernel(const float* __restrict__ partial, float* __restrict__ w, int N) {
  const int r    = blockIdx.x * 4 + (threadIdx.x >> 6);
  const int lane = threadIdx.x & 63;
  const float* p = partial + ((size_t)r * 64 + lane) * 5;
  float t[5];
  #pragma unroll
  for (int j = 0; j < 5; ++j) t[j] = p[j];   // each slot already sorted ascending
  #pragma unroll
  for (int off = 1; off < 64; off <<= 1) {
    float o[5];
    #pragma unroll
    for (int j = 0; j < 5; ++j) o[j] = __shfl_xor(t[j], off, 64);
    #pragma unroll
    for (int j = 0; j < 5; ++j) insert5(t, o[j]);
  }
  if (lane == 0) {
    float sc = 0.f;
    #pragma unroll
    for (int j = 0; j < 5; ++j) sc += sqrtf(fmaxf(t[j], 0.f));
    sc *= 0.2f;  // mean of 5
    w[r] = (sc > PTH) ? expf(-sc / TAU) : 0.f;
  }
}

__global__ void apply_kernel(const float* __restrict__ xr, const float* __restrict__ xi,
                             const float* __restrict__ w, float* __restrict__ out, int N) {
  const size_t i = (size_t)blockIdx.x * blockDim.x + threadIdx.x;
  const size_t tot = (size_t)N * (DD / 4);
  if (i >= tot) return;
  const int row = (int)(i >> 8);  // DD/4 = 256 float4 per row
  const float wt = w[row];
  float4 a = reinterpret_cast<const float4*>(xr)[i];
  a.x *= wt; a.y *= wt; a.z *= wt; a.w *= wt;
  reinterpret_cast<float4*>(out)[i] = a;
  float4 b = reinterpret_cast<const float4*>(xi)[i];
  b.x *= wt; b.y *= wt; b.z *= wt; b.w *= wt;
  reinterpret_cast<float4*>(out)[tot + i] = b;
}

extern "C" void kernel_launch(void* const* d_in, const int* in_sizes, int n_in,
                              void* d_out, int out_size, void* d_ws, size_t ws_size,
                              hipStream_t stream) {
  const float* xr = (const float*)d_in[0];
  const float* xi = (const float*)d_in[1];
  float* out = (float*)d_out;
  const int N = in_sizes[0] / DD;  // 8192
  const int NBv = N / BM;          // 64
  const int NSB = NBv / 8;         // 8

  unsigned short* xbf = (unsigned short*)d_ws;                       // N*DD bf16
  float* sq      = (float*)((char*)d_ws + (size_t)N * DD * 2);       // N f32
  float* partial = sq + N;                                           // N*NBv*5 f32 (10.5 MB)
  float* w       = partial + (size_t)N * NBv * 5;                    // N f32

  prep_kernel<<<N / 4, 256, 0, stream>>>(xr, xbf, sq);
  const int nsp = NSB * (NSB + 1) / 2;      // 36 super-pairs
  gemm_topk_kernel<<<nsp * 64, 256, 0, stream>>>(xbf, sq, partial, N);  // 2304 blocks
  weight_kernel<<<N / 4, 256, 0, stream>>>(partial, w, N);
  apply_kernel<<<N, 256, 0, stream>>>(xr, xi, w, out, N);
}

// Round 11
// 143.731 us; speedup vs baseline: 1.6237x; 1.6237x over previous
//
#include <hip/hip_runtime.h>
#include <hip/hip_bf16.h>

#define DD 1024            // bytes per row in fp8 (= elems)
#define BM 128
#define BN 128
#define BK 64              // 64 fp8 elems = 64 B per row per tile
#define NKT (DD / BK)      // 16 K-tiles
#define TAU 32.0f
#define PTH 0.1f
#define BIGF 3.0e38f

typedef __attribute__((ext_vector_type(4))) float f32x4;

// f32 -> OCP e4m3fn (RNE, saturate to 448, subnormal support)
__device__ __forceinline__ unsigned char f2e4m3(float f) {
  unsigned u = __float_as_uint(f);
  unsigned s = (u >> 24) & 0x80u;
  unsigned au = u & 0x7fffffffu;
  if (au >= 0x43E00000u) return (unsigned char)(s | 0x7E);     // clamp >= 448
  if (au < 0x3C800000u) {                                      // |f| < 2^-6: subnormal
    int m = (int)rintf(__uint_as_float(au) * 512.0f);          // steps of 2^-9
    if (m > 7) return (unsigned char)(s | 0x08);
    return (unsigned char)(s | (unsigned)m);
  }
  unsigned tmp = au + 0x0007FFFFu + ((au >> 20) & 1u);         // RNE at mantissa bit 20
  unsigned e4 = (tmp >> 23) - 120u;                            // rebias 127 -> 7
  if (e4 >= 16u) return (unsigned char)(s | 0x7E);
  return (unsigned char)(s | (e4 << 3) | ((tmp >> 20) & 7u));
}

// sorted-ascending top-5-smallest insert via med3: 5 independent VALU ops
__device__ __forceinline__ void insert5(float (&t)[5], float v) {
  float t0 = t[0], t1 = t[1], t2 = t[2], t3 = t[3], t4 = t[4];
  t[0] = fminf(t0, v);
  t[1] = __builtin_amdgcn_fmed3f(v, t0, t1);
  t[2] = __builtin_amdgcn_fmed3f(v, t1, t2);
  t[3] = __builtin_amdgcn_fmed3f(v, t2, t3);
  t[4] = __builtin_amdgcn_fmed3f(v, t3, t4);
}

__device__ __forceinline__ void gload16(const unsigned char* g, unsigned char* l) {
  __builtin_amdgcn_global_load_lds(
      (const __attribute__((address_space(1))) void*)g,
      (__attribute__((address_space(3))) void*)l, 16, 0, 0);
}

// one wave per row: squared norm (f32, exact) + fp8 e4m3 cast of X
__global__ void prep_kernel(const float* __restrict__ x, unsigned char* __restrict__ x8,
                            float* __restrict__ sq) {
  const int row  = blockIdx.x * 4 + (threadIdx.x >> 6);
  const int lane = threadIdx.x & 63;
  const float4* xr = reinterpret_cast<const float4*>(x) + (size_t)row * (DD / 4);
  float s = 0.f;
  #pragma unroll
  for (int i = 0; i < 4; ++i) {
    float4 v = xr[lane + 64 * i];
    s += v.x * v.x + v.y * v.y + v.z * v.z + v.w * v.w;
    uchar4 b;
    b.x = f2e4m3(v.x); b.y = f2e4m3(v.y); b.z = f2e4m3(v.z); b.w = f2e4m3(v.w);
    *reinterpret_cast<uchar4*>(x8 + (size_t)row * DD + (size_t)(lane + 64 * i) * 4) = b;
  }
  #pragma unroll
  for (int off = 32; off > 0; off >>= 1) s += __shfl_xor(s, off, 64);
  if (lane == 0) sq[row] = s;
}

// Symmetric flash top-k over upper-triangle 128x128 block-pairs (I,J), 8x8
// super-tiles + XCD swizzle. fp8 e4m3 GEMM (16x16x32_fp8_fp8, bf16 MFMA rate,
// half the staging bytes). Tiles double-buffered (2 x 16 KB < 41 KB merge
// union -> still 3 blocks/CU); stage(t+1) issues before compute(t), drained
// by the single per-iter __syncthreads.
__global__ __launch_bounds__(256, 3)
void gemm_topk_kernel(const unsigned char* __restrict__ x8, const float* __restrict__ sq,
                      float* __restrict__ partial, int N) {
  struct Tiles { unsigned char A[BM * BK]; unsigned char B[BN * BK]; };  // 16 KB
  __shared__ union ShMem {
    Tiles tl[2];           // 32 KB double buffer
    float mrg[64 * 161];   // row-merge: row*161 + contrib*5 + j  (41.2 KB)
    float mrgc[128 * 41];  // col-merge: col*41 + contrib*5 + j   (21 KB)
  } sh;
  static_assert(sizeof(ShMem) <= 65536, "LDS over 64KB");

  const int tid  = threadIdx.x;
  const int lane = tid & 63;
  const int wid  = tid >> 6;
  const int wr   = wid >> 1;   // 0..1 -> 64-row half
  const int wc   = wid & 1;    // 0..1 -> 64-col half
  const int l15  = lane & 15;
  const int l4   = lane >> 4;  // 0..3

  const int NBv = N / BM;      // 64 block-rows
  const int NSB = NBv / 8;     // 8 super-rows

  // bijective chunked XCD swizzle (gridDim.x divisible by 8)
  const int chunk = gridDim.x >> 3;
  const int swz = (blockIdx.x & 7) * chunk + (blockIdx.x >> 3);
  const int sp  = swz >> 6;    // super-pair (triangle over NSB)
  const int sub = swz & 63;

  int SI = 0;
  #define TSTART(i) ((i) * NSB - ((i) * ((i) - 1)) / 2)
  while (SI + 1 < NSB && TSTART(SI + 1) <= sp) ++SI;
  const int SJ = SI + (sp - TSTART(SI));
  #undef TSTART
  const int si = sub >> 3, sj = sub & 7;
  if (SI == SJ && si > sj) return;  // lower-triangle sub-pair of diagonal super-pair
  const int I = SI * 8 + si, J = SJ * 8 + sj;

  const int row0 = I * BM;
  const int cb   = J * BM;
  const bool diag = (I == J);

  // DMA staging: instruction j covers rows j*16..j*16+15 (1 KB linear LDS).
  // lane -> row = j*16 + (lane>>2), phys 16B slot = lane&3.
  // LDS slot swizzle: phys = logical ^ (row&3)  => source k-slot = (lane&3)^(row&3).
  const int srow = lane >> 2;
  const size_t offl = (size_t)srow * DD + (size_t)(((lane & 3) ^ (srow & 3)) * 16);
  const unsigned char* srcA = x8 + (size_t)row0 * DD + offl;
  const unsigned char* srcB = x8 + (size_t)cb * DD + offl;

  // fragment read offsets within a 64B row (b64 read: 8 fp8 = one frag):
  // logical byte = ks*32 + l4*8 -> 16B slot ks*2+(l4>>1) (^ row&3), half l4&1
  const int rm3 = l15 & 3;
  const int xs0 = (((0 * 2 + (l4 >> 1)) ^ rm3) * 16) + (l4 & 1) * 8;  // ks=0
  const int xs1 = (((1 * 2 + (l4 >> 1)) ^ rm3) * 16) + (l4 & 1) * 8;  // ks=1

  f32x4 acc[4][4];
  #pragma unroll
  for (int mi = 0; mi < 4; ++mi)
    #pragma unroll
    for (int ni = 0; ni < 4; ++ni) {
      f32x4 z; z[0] = 0.f; z[1] = 0.f; z[2] = 0.f; z[3] = 0.f;
      acc[mi][ni] = z;
    }

#define STAGE(kt, b) { const size_t kk = (size_t)(kt) * BK;                       \
    _Pragma("unroll") for (int jj = 0; jj < 2; ++jj) {                            \
      const int j = wid * 2 + jj;                                                 \
      gload16(srcA + (size_t)j * 16 * DD + kk, sh.tl[b].A + j * 1024);            \
      gload16(srcB + (size_t)j * 16 * DD + kk, sh.tl[b].B + j * 1024); } }

#define COMPUTE(b) {                                                              \
    _Pragma("unroll") for (int ks = 0; ks < 2; ++ks) {                            \
      const int xs = ks ? xs1 : xs0;                                              \
      long af[4], bfr[4];                                                         \
      _Pragma("unroll") for (int mi = 0; mi < 4; ++mi)                            \
        af[mi] = *reinterpret_cast<const long*>(sh.tl[b].A + (wr * 64 + mi * 16 + l15) * BK + xs); \
      _Pragma("unroll") for (int ni = 0; ni < 4; ++ni)                            \
        bfr[ni] = *reinterpret_cast<const long*>(sh.tl[b].B + (wc * 64 + ni * 16 + l15) * BK + xs); \
      _Pragma("unroll") for (int mi = 0; mi < 4; ++mi)                            \
        _Pragma("unroll") for (int ni = 0; ni < 4; ++ni)                          \
          acc[mi][ni] = __builtin_amdgcn_mfma_f32_16x16x32_fp8_fp8(af[mi], bfr[ni], acc[mi][ni], 0, 0, 0); } }

  // prologue: stage tile 0 -> buf0
  STAGE(0, 0);

  for (int t = 0; t < NKT; ++t) {
    __syncthreads();           // drains vmcnt -> buf[t&1] ready; prev reads done
    const int cur = t & 1;
    if (t + 1 < NKT) STAGE(t + 1, cur ^ 1);  // latency hides under compute(t)
    COMPUTE(cur);
  }

  // d^2 = sq_r + sq_c - 2*dot; fold row-side (t5r) and, off-diag, col-side (t5c)
  float t5r[16][5], t5c[4][5];
  #pragma unroll
  for (int i = 0; i < 16; ++i)
    #pragma unroll
    for (int j = 0; j < 5; ++j) t5r[i][j] = BIGF;
  #pragma unroll
  for (int i = 0; i < 4; ++i)
    #pragma unroll
    for (int j = 0; j < 5; ++j) t5c[i][j] = BIGF;

  float sqr_[16];
  #pragma unroll
  for (int mi = 0; mi < 4; ++mi)
    #pragma unroll
    for (int r = 0; r < 4; ++r)
      sqr_[mi * 4 + r] = sq[row0 + wr * 64 + mi * 16 + l4 * 4 + r];

  #pragma unroll
  for (int ni = 0; ni < 4; ++ni) {
    const int gc = cb + wc * 64 + ni * 16 + l15;
    const float sqc = sq[gc];
    #pragma unroll
    for (int mi = 0; mi < 4; ++mi) {
      #pragma unroll
      for (int r = 0; r < 4; ++r) {
        float v = fmaf(-2.0f, acc[mi][ni][r], sqr_[mi * 4 + r] + sqc);
        if (diag) {
          const int gr = row0 + wr * 64 + mi * 16 + l4 * 4 + r;
          v = (gc == gr) ? BIGF : v;  // exclude self
        }
        insert5(t5r[mi * 4 + r], v);
        if (!diag) insert5(t5c[ni], v);
      }
    }
  }

  // row-side merge in two passes (64 rows each; 32 contributors per row) -> slot J
  #pragma unroll
  for (int pass = 0; pass < 2; ++pass) {
    __syncthreads();
    if (wr == pass) {
      #pragma unroll
      for (int mi = 0; mi < 4; ++mi)
        #pragma unroll
        for (int r = 0; r < 4; ++r)
          #pragma unroll
          for (int j = 0; j < 5; ++j)
            sh.mrg[(mi * 16 + l4 * 4 + r) * 161 + (wc * 16 + l15) * 5 + j] = t5r[mi * 4 + r][j];
    }
    __syncthreads();
    if (tid < 64) {
      float m[5] = {BIGF, BIGF, BIGF, BIGF, BIGF};
      for (int s2 = 0; s2 < 32; ++s2)
        #pragma unroll
        for (int j = 0; j < 5; ++j)
          insert5(m, sh.mrg[tid * 161 + s2 * 5 + j]);
      float* p = partial + ((size_t)(row0 + pass * 64 + tid) * NBv + J) * 5;
      #pragma unroll
      for (int j = 0; j < 5; ++j) p[j] = m[j];
    }
  }

  // col-side merge (128 cols; 8 contributors per col) -> rows of block J, slot I
  if (!diag) {
    __syncthreads();
    #pragma unroll
    for (int ni = 0; ni < 4; ++ni)
      #pragma unroll
      for (int j = 0; j < 5; ++j)
        sh.mrgc[(wc * 64 + ni * 16 + l15) * 41 + (wr * 4 + l4) * 5 + j] = t5c[ni][j];
    __syncthreads();
    if (tid < 128) {
      float m[5] = {BIGF, BIGF, BIGF, BIGF, BIGF};
      #pragma unroll
      for (int s2 = 0; s2 < 8; ++s2)
        #pragma unroll
        for (int j = 0; j < 5; ++j)
          insert5(m, sh.mrgc[tid * 41 + s2 * 5 + j]);
      float* p = partial + ((size_t)(cb + tid) * NBv + I) * 5;
      #pragma unroll
      for (int j = 0; j < 5; ++j) p[j] = m[j];
    }
  }
}

// one wave per row: parallel load of 64 slot-top5s + butterfly shuffle merge
__global__ void weight_kernel(const float* __restrict__ partial, float* __restrict__ w, int N) {
  const int r    = blockIdx.x * 4 + (threadIdx.x >> 6);
  const int lane = threadIdx.x & 63;
  const float* p = partial + ((size_t)r * 64 + lane) * 5;
  float t[5];
  #pragma unroll
  for (int j = 0; j < 5; ++j) t[j] = p[j];   // each slot already sorted ascending
  #pragma unroll
  for (int off = 1; off < 64; off <<= 1) {
    float o[5];
    #pragma unroll
    for (int j = 0; j < 5; ++j) o[j] = __shfl_xor(t[j], off, 64);
    #pragma unroll
    for (int j = 0; j < 5; ++j) insert5(t, o[j]);
  }
  if (lane == 0) {
    float sc = 0.f;
    #pragma unroll
    for (int j = 0; j < 5; ++j) sc += sqrtf(fmaxf(t[j], 0.f));
    sc *= 0.2f;  // mean of 5
    w[r] = (sc > PTH) ? expf(-sc / TAU) : 0.f;
  }
}

__global__ void apply_kernel(const float* __restrict__ xr, const float* __restrict__ xi,
                             const float* __restrict__ w, float* __restrict__ out, int N) {
  const size_t i = (size_t)blockIdx.x * blockDim.x + threadIdx.x;
  const size_t tot = (size_t)N * (DD / 4);
  if (i >= tot) return;
  const int row = (int)(i >> 8);  // DD/4 = 256 float4 per row
  const float wt = w[row];
  float4 a = reinterpret_cast<const float4*>(xr)[i];
  a.x *= wt; a.y *= wt; a.z *= wt; a.w *= wt;
  reinterpret_cast<float4*>(out)[i] = a;
  float4 b = reinterpret_cast<const float4*>(xi)[i];
  b.x *= wt; b.y *= wt; b.z *= wt; b.w *= wt;
  reinterpret_cast<float4*>(out)[tot + i] = b;
}

extern "C" void kernel_launch(void* const* d_in, const int* in_sizes, int n_in,
                              void* d_out, int out_size, void* d_ws, size_t ws_size,
                              hipStream_t stream) {
  const float* xr = (const float*)d_in[0];
  const float* xi = (const float*)d_in[1];
  float* out = (float*)d_out;
  const int N = in_sizes[0] / DD;  // 8192
  const int NBv = N / BM;          // 64
  const int NSB = NBv / 8;         // 8

  unsigned char* x8 = (unsigned char*)d_ws;                          // N*DD fp8 (8 MB)
  float* sq      = (float*)((char*)d_ws + (size_t)N * DD);           // N f32
  float* partial = sq + N;                                           // N*NBv*5 f32 (10.5 MB)
  float* w       = partial + (size_t)N * NBv * 5;                    // N f32

  prep_kernel<<<N / 4, 256, 0, stream>>>(xr, x8, sq);
  const int nsp = NSB * (NSB + 1) / 2;      // 36 super-pairs
  gemm_topk_kernel<<<nsp * 64, 256, 0, stream>>>(x8, sq, partial, N);  // 2304 blocks
  weight_kernel<<<N / 4, 256, 0, stream>>>(partial, w, N);
  apply_kernel<<<N, 256, 0, stream>>>(xr, xi, w, out, N);
}

// Round 12
// 121.325 us; speedup vs baseline: 1.9235x; 1.1847x over previous
//
#include <hip/hip_runtime.h>
#include <hip/hip_bf16.h>

#define DD 1024            // fp8 elems per row (= bytes)
#define BM 128
#define BN 128
#define BK 128             // fp8 elems per K-tile -> 128 B rows (proven geometry)
#define NKT (DD / BK)      // 8 K-tiles
#define TAU 32.0f
#define PTH 0.1f
#define BIGF 3.0e38f

typedef __attribute__((ext_vector_type(4))) float f32x4;
typedef __attribute__((ext_vector_type(2))) long i64x2;

// f32 -> OCP e4m3fn (RNE, saturate to 448, subnormal support)
__device__ __forceinline__ unsigned char f2e4m3(float f) {
  unsigned u = __float_as_uint(f);
  unsigned s = (u >> 24) & 0x80u;
  unsigned au = u & 0x7fffffffu;
  if (au >= 0x43E00000u) return (unsigned char)(s | 0x7E);     // clamp >= 448
  if (au < 0x3C800000u) {                                      // |f| < 2^-6: subnormal
    int m = (int)rintf(__uint_as_float(au) * 512.0f);          // steps of 2^-9
    if (m > 7) return (unsigned char)(s | 0x08);
    return (unsigned char)(s | (unsigned)m);
  }
  unsigned tmp = au + 0x0007FFFFu + ((au >> 20) & 1u);         // RNE at mantissa bit 20
  unsigned e4 = (tmp >> 23) - 120u;                            // rebias 127 -> 7
  if (e4 >= 16u) return (unsigned char)(s | 0x7E);
  return (unsigned char)(s | (e4 << 3) | ((tmp >> 20) & 7u));
}

// sorted-ascending top-5-smallest insert via med3: 5 independent VALU ops
__device__ __forceinline__ void insert5(float (&t)[5], float v) {
  float t0 = t[0], t1 = t[1], t2 = t[2], t3 = t[3], t4 = t[4];
  t[0] = fminf(t0, v);
  t[1] = __builtin_amdgcn_fmed3f(v, t0, t1);
  t[2] = __builtin_amdgcn_fmed3f(v, t1, t2);
  t[3] = __builtin_amdgcn_fmed3f(v, t2, t3);
  t[4] = __builtin_amdgcn_fmed3f(v, t3, t4);
}

__device__ __forceinline__ void gload16(const unsigned char* g, unsigned char* l) {
  __builtin_amdgcn_global_load_lds(
      (const __attribute__((address_space(1))) void*)g,
      (__attribute__((address_space(3))) void*)l, 16, 0, 0);
}

// one wave per row: squared norm (f32, exact) + fp8 cast, K bit-field-permuted:
// within each 128-block, position p holds logical k with q[3:4]<->q[5:6] swapped
// (self-inverse; identical permutation on both GEMM operands => X.X^T unchanged).
// Result: lane l4's four MFMA k-chunks (k=ks*32+l4*8) are CONTIGUOUS 32 B.
__global__ void prep_kernel(const float* __restrict__ x, unsigned char* __restrict__ x8,
                            float* __restrict__ sq) {
  const int row  = blockIdx.x * 4 + (threadIdx.x >> 6);
  const int lane = threadIdx.x & 63;
  const float4* xr = reinterpret_cast<const float4*>(x) + (size_t)row * (DD / 4);
  float s = 0.f;
  #pragma unroll
  for (int i = 0; i < 4; ++i) {
    float4 v = xr[lane + 64 * i];
    s += v.x * v.x + v.y * v.y + v.z * v.z + v.w * v.w;
    uchar4 b;
    b.x = f2e4m3(v.x); b.y = f2e4m3(v.y); b.z = f2e4m3(v.z); b.w = f2e4m3(v.w);
    const int k0 = (lane + 64 * i) * 4;
    const int q  = k0 & 127;
    const int p  = (k0 & ~127) + ((q >> 3) & 3) * 32 + ((q >> 5) & 3) * 8 + (q & 7);
    *reinterpret_cast<uchar4*>(x8 + (size_t)row * DD + p) = b;
  }
  #pragma unroll
  for (int off = 32; off > 0; off >>= 1) s += __shfl_xor(s, off, 64);
  if (lane == 0) sq[row] = s;
}

// Symmetric flash top-k over upper-triangle 128x128 block-pairs (I,J), 8x8
// super-tiles + XCD swizzle. fp8 e4m3 GEMM, BK=128 (128B rows): same XOR-slot
// swizzle + gload_lds staging geometry as the proven bf16 kernel, but half the
// iterations -> half the barrier/drain/staging overhead. Single-buffered 32 KB
// tiles union'd with merge scratch -> 3 blocks/CU.
__global__ __launch_bounds__(256, 3)
void gemm_topk_kernel(const unsigned char* __restrict__ x8, const float* __restrict__ sq,
                      float* __restrict__ partial, int N) {
  __shared__ union ShMem {
    struct { unsigned char A[BM * BK]; unsigned char B[BN * BK]; } tl;  // 32 KB
    float mrg[64 * 161];   // row-merge: row*161 + contrib*5 + j  (41.2 KB)
    float mrgc[128 * 41];  // col-merge: col*41 + contrib*5 + j   (21 KB)
  } sh;
  static_assert(sizeof(ShMem) <= 65536, "LDS over 64KB");

  const int tid  = threadIdx.x;
  const int lane = tid & 63;
  const int wid  = tid >> 6;
  const int wr   = wid >> 1;   // 0..1 -> 64-row half
  const int wc   = wid & 1;    // 0..1 -> 64-col half
  const int l15  = lane & 15;
  const int l4   = lane >> 4;  // 0..3

  const int NBv = N / BM;      // 64 block-rows
  const int NSB = NBv / 8;     // 8 super-rows

  // bijective chunked XCD swizzle (gridDim.x divisible by 8)
  const int chunk = gridDim.x >> 3;
  const int swz = (blockIdx.x & 7) * chunk + (blockIdx.x >> 3);
  const int sp  = swz >> 6;    // super-pair (triangle over NSB)
  const int sub = swz & 63;

  int SI = 0;
  #define TSTART(i) ((i) * NSB - ((i) * ((i) - 1)) / 2)
  while (SI + 1 < NSB && TSTART(SI + 1) <= sp) ++SI;
  const int SJ = SI + (sp - TSTART(SI));
  #undef TSTART
  const int si = sub >> 3, sj = sub & 7;
  if (SI == SJ && si > sj) return;  // lower-triangle sub-pair of diagonal super-pair
  const int I = SI * 8 + si, J = SJ * 8 + sj;

  const int row0 = I * BM;
  const int cb   = J * BM;
  const bool diag = (I == J);

  // DMA staging (same as proven bf16 geometry): instruction j covers rows
  // j*8..j*8+7 (1 KB linear LDS). lane -> row j*8 + (lane>>3), phys slot lane&7
  // holds logical slot (lane&7)^(row&7); row&7 == lane>>3.
  const int lr = lane >> 3;
  const int lc = (lane & 7) ^ lr;
  const size_t offl = (size_t)lr * DD + (size_t)lc * 16;
  const int jbase = wid * 4;
  const unsigned char* srcA = x8 + (size_t)row0 * DD + offl;
  const unsigned char* srcB = x8 + (size_t)cb * DD + offl;

  f32x4 acc[4][4];
  #pragma unroll
  for (int mi = 0; mi < 4; ++mi)
    #pragma unroll
    for (int ni = 0; ni < 4; ++ni) {
      f32x4 z; z[0] = 0.f; z[1] = 0.f; z[2] = 0.f; z[3] = 0.f;
      acc[mi][ni] = z;
    }

  // fragment reads: lane's 32 contiguous logical bytes at row*BK + l4*32,
  // as two b128 chunks c=0,1 at phys slot (l4*2+c)^(row&7); row&7 == l15&7
  const int ps0 = ((l4 * 2 + 0) ^ (l15 & 7)) * 16;
  const int ps1 = ((l4 * 2 + 1) ^ (l15 & 7)) * 16;

#define STAGE(kt) { const size_t kk = (size_t)(kt) * BK;                          \
    _Pragma("unroll") for (int jj = 0; jj < 4; ++jj) {                            \
      const int j = jbase + jj;                                                   \
      gload16(srcA + (size_t)j * 8 * DD + kk, sh.tl.A + j * 1024);                \
      gload16(srcB + (size_t)j * 8 * DD + kk, sh.tl.B + j * 1024); } }

#define COMPUTE() {                                                               \
    i64x2 af[4][2], bfr[4][2];                                                    \
    _Pragma("unroll") for (int mi = 0; mi < 4; ++mi) {                            \
      const unsigned char* rp = sh.tl.A + (wr * 64 + mi * 16 + l15) * BK;         \
      af[mi][0] = *reinterpret_cast<const i64x2*>(rp + ps0);                      \
      af[mi][1] = *reinterpret_cast<const i64x2*>(rp + ps1); }                    \
    _Pragma("unroll") for (int ni = 0; ni < 4; ++ni) {                            \
      const unsigned char* rp = sh.tl.B + (wc * 64 + ni * 16 + l15) * BK;         \
      bfr[ni][0] = *reinterpret_cast<const i64x2*>(rp + ps0);                     \
      bfr[ni][1] = *reinterpret_cast<const i64x2*>(rp + ps1); }                   \
    _Pragma("unroll") for (int ks = 0; ks < 4; ++ks)                              \
      _Pragma("unroll") for (int mi = 0; mi < 4; ++mi)                            \
        _Pragma("unroll") for (int ni = 0; ni < 4; ++ni)                          \
          acc[mi][ni] = __builtin_amdgcn_mfma_f32_16x16x32_fp8_fp8(               \
              af[mi][ks >> 1][ks & 1], bfr[ni][ks >> 1][ks & 1], acc[mi][ni], 0, 0, 0); }

  for (int t = 0; t < NKT; ++t) {
    __syncthreads();           // prior LDS reads done
    STAGE(t);
    __syncthreads();           // vmcnt(0) drained -> tile landed
    COMPUTE();
  }

  // d^2 = sq_r + sq_c - 2*dot; fold row-side (t5r) and, off-diag, col-side (t5c)
  float t5r[16][5], t5c[4][5];
  #pragma unroll
  for (int i = 0; i < 16; ++i)
    #pragma unroll
    for (int j = 0; j < 5; ++j) t5r[i][j] = BIGF;
  #pragma unroll
  for (int i = 0; i < 4; ++i)
    #pragma unroll
    for (int j = 0; j < 5; ++j) t5c[i][j] = BIGF;

  float sqr_[16];
  #pragma unroll
  for (int mi = 0; mi < 4; ++mi)
    #pragma unroll
    for (int r = 0; r < 4; ++r)
      sqr_[mi * 4 + r] = sq[row0 + wr * 64 + mi * 16 + l4 * 4 + r];

  #pragma unroll
  for (int ni = 0; ni < 4; ++ni) {
    const int gc = cb + wc * 64 + ni * 16 + l15;
    const float sqc = sq[gc];
    #pragma unroll
    for (int mi = 0; mi < 4; ++mi) {
      #pragma unroll
      for (int r = 0; r < 4; ++r) {
        float v = fmaf(-2.0f, acc[mi][ni][r], sqr_[mi * 4 + r] + sqc);
        if (diag) {
          const int gr = row0 + wr * 64 + mi * 16 + l4 * 4 + r;
          v = (gc == gr) ? BIGF : v;  // exclude self
        }
        insert5(t5r[mi * 4 + r], v);
        if (!diag) insert5(t5c[ni], v);
      }
    }
  }

  // row-side merge in two passes (64 rows each; 32 contributors per row) -> slot J
  #pragma unroll
  for (int pass = 0; pass < 2; ++pass) {
    __syncthreads();
    if (wr == pass) {
      #pragma unroll
      for (int mi = 0; mi < 4; ++mi)
        #pragma unroll
        for (int r = 0; r < 4; ++r)
          #pragma unroll
          for (int j = 0; j < 5; ++j)
            sh.mrg[(mi * 16 + l4 * 4 + r) * 161 + (wc * 16 + l15) * 5 + j] = t5r[mi * 4 + r][j];
    }
    __syncthreads();
    if (tid < 64) {
      float m[5] = {BIGF, BIGF, BIGF, BIGF, BIGF};
      for (int s2 = 0; s2 < 32; ++s2)
        #pragma unroll
        for (int j = 0; j < 5; ++j)
          insert5(m, sh.mrg[tid * 161 + s2 * 5 + j]);
      float* p = partial + ((size_t)(row0 + pass * 64 + tid) * NBv + J) * 5;
      #pragma unroll
      for (int j = 0; j < 5; ++j) p[j] = m[j];
    }
  }

  // col-side merge (128 cols; 8 contributors per col) -> rows of block J, slot I
  if (!diag) {
    __syncthreads();
    #pragma unroll
    for (int ni = 0; ni < 4; ++ni)
      #pragma unroll
      for (int j = 0; j < 5; ++j)
        sh.mrgc[(wc * 64 + ni * 16 + l15) * 41 + (wr * 4 + l4) * 5 + j] = t5c[ni][j];
    __syncthreads();
    if (tid < 128) {
      float m[5] = {BIGF, BIGF, BIGF, BIGF, BIGF};
      #pragma unroll
      for (int s2 = 0; s2 < 8; ++s2)
        #pragma unroll
        for (int j = 0; j < 5; ++j)
          insert5(m, sh.mrgc[tid * 41 + s2 * 5 + j]);
      float* p = partial + ((size_t)(cb + tid) * NBv + I) * 5;
      #pragma unroll
      for (int j = 0; j < 5; ++j) p[j] = m[j];
    }
  }
}

// one wave per row: parallel load of 64 slot-top5s + butterfly shuffle merge
__global__ void weight_kernel(const float* __restrict__ partial, float* __restrict__ w, int N) {
  const int r    = blockIdx.x * 4 + (threadIdx.x >> 6);
  const int lane = threadIdx.x & 63;
  const float* p = partial + ((size_t)r * 64 + lane) * 5;
  float t[5];
  #pragma unroll
  for (int j = 0; j < 5; ++j) t[j] = p[j];   // each slot already sorted ascending
  #pragma unroll
  for (int off = 1; off < 64; off <<= 1) {
    float o[5];
    #pragma unroll
    for (int j = 0; j < 5; ++j) o[j] = __shfl_xor(t[j], off, 64);
    #pragma unroll
    for (int j = 0; j < 5; ++j) insert5(t, o[j]);
  }
  if (lane == 0) {
    float sc = 0.f;
    #pragma unroll
    for (int j = 0; j < 5; ++j) sc += sqrtf(fmaxf(t[j], 0.f));
    sc *= 0.2f;  // mean of 5
    w[r] = (sc > PTH) ? expf(-sc / TAU) : 0.f;
  }
}

__global__ void apply_kernel(const float* __restrict__ xr, const float* __restrict__ xi,
                             const float* __restrict__ w, float* __restrict__ out, int N) {
  const size_t i = (size_t)blockIdx.x * blockDim.x + threadIdx.x;
  const size_t tot = (size_t)N * (DD / 4);
  if (i >= tot) return;
  const int row = (int)(i >> 8);  // DD/4 = 256 float4 per row
  const float wt = w[row];
  float4 a = reinterpret_cast<const float4*>(xr)[i];
  a.x *= wt; a.y *= wt; a.z *= wt; a.w *= wt;
  reinterpret_cast<float4*>(out)[i] = a;
  float4 b = reinterpret_cast<const float4*>(xi)[i];
  b.x *= wt; b.y *= wt; b.z *= wt; b.w *= wt;
  reinterpret_cast<float4*>(out)[tot + i] = b;
}

extern "C" void kernel_launch(void* const* d_in, const int* in_sizes, int n_in,
                              void* d_out, int out_size, void* d_ws, size_t ws_size,
                              hipStream_t stream) {
  const float* xr = (const float*)d_in[0];
  const float* xi = (const float*)d_in[1];
  float* out = (float*)d_out;
  const int N = in_sizes[0] / DD;  // 8192
  const int NBv = N / BM;          // 64
  const int NSB = NBv / 8;         // 8

  unsigned char* x8 = (unsigned char*)d_ws;                          // N*DD fp8 (8 MB)
  float* sq      = (float*)((char*)d_ws + (size_t)N * DD);           // N f32
  float* partial = sq + N;                                           // N*NBv*5 f32 (10.5 MB)
  float* w       = partial + (size_t)N * NBv * 5;                    // N f32

  prep_kernel<<<N / 4, 256, 0, stream>>>(xr, x8, sq);
  const int nsp = NSB * (NSB + 1) / 2;      // 36 super-pairs
  gemm_topk_kernel<<<nsp * 64, 256, 0, stream>>>(x8, sq, partial, N);  // 2304 blocks
  weight_kernel<<<N / 4, 256, 0, stream>>>(partial, w, N);
  apply_kernel<<<N, 256, 0, stream>>>(xr, xi, w, out, N);
}